// Round 2
// baseline (1222.301 us; speedup 1.0000x reference)
//
#include <hip/hip_runtime.h>

typedef unsigned int uint32;
typedef __attribute__((ext_vector_type(8))) short short8;
typedef __attribute__((ext_vector_type(4))) float floatx4;

#define B_TOK 1024
#define TOPK 4
#define NEXP 16
#define H_DIM 2048
#define I_DIM 2048
#define NSLOT 4096           // B_TOK * TOPK
#define CAP 512              // per-expert row capacity (mean 256, sigma ~15.5)
#define C1 4096              // 2*I_DIM, gate_up rows
#define SLOT_ROWS 8192       // NEXP * CAP

#define TM 128
#define TN 128
#define BK 32
#define NTH 256
#define CVT_Y 16             // converter y-rows fused into k_gemm1 grid
#define N8_WG (NEXP * C1 * H_DIM / 8)      // 16,777,216 8-float groups
#define N8_WD (NEXP * H_DIM * I_DIM / 8)   //  8,388,608 8-float groups

// fp32 -> bf16 round-to-nearest-even
__device__ __forceinline__ unsigned short f2bf(float x) {
  unsigned int u = __float_as_uint(x);
  u += 0x7fffu + ((u >> 16) & 1u);
  return (unsigned short)(u >> 16);
}

// pack two fp32 -> bf16x2 with round-half-up: 2 adds + 1 v_perm
__device__ __forceinline__ uint32 pk2bf(float a, float b) {
  uint32 ua = __float_as_uint(a) + 0x8000u;
  uint32 ub = __float_as_uint(b) + 0x8000u;
  return __builtin_amdgcn_perm(ub, ua, 0x07060302u);
}

// async global -> LDS, 16 bytes per lane. LDS dest is wave-uniform base + lane*16.
typedef const unsigned int __attribute__((address_space(1))) cu32_g;
typedef unsigned int __attribute__((address_space(3))) u32_l;
__device__ __forceinline__ void ldst16(void* lds, const void* g) {
  __builtin_amdgcn_global_load_lds((cu32_g*)g, (u32_l*)lds, 16, 0, 0);
}

// k_setup: t fp32->bf16, slot/count init, and Wg fp32->bf16 (grid-stride).
__global__ __launch_bounds__(256) void k_setup(
    const float* __restrict__ t, unsigned short* __restrict__ t_bf,
    int* __restrict__ sorted_slots, int* __restrict__ counts,
    const float* __restrict__ Wg, unsigned short* __restrict__ Wg_bf) {
  int gid = blockIdx.x * blockDim.x + threadIdx.x;
  const float4* tp = (const float4*)t;
  float4 v = tp[gid];
  ushort4 o;
  o.x = f2bf(v.x); o.y = f2bf(v.y); o.z = f2bf(v.z); o.w = f2bf(v.w);
  ((ushort4*)t_bf)[gid] = o;
  if (gid < SLOT_ROWS) sorted_slots[gid] = 0;   // padding rows -> slot 0 (safe token)
  if (gid < NEXP) counts[gid] = 0;

  // Wg conversion: 512 MB read + 256 MB write, HBM-bound (~120 us)
  const float4* s4 = (const float4*)Wg;
  uint4* d4 = (uint4*)Wg_bf;
  const int stride = gridDim.x * 256;
  for (int i = gid; i < N8_WG; i += stride) {
    float4 v0 = s4[2 * i], v1 = s4[2 * i + 1];
    uint4 w;
    w.x = pk2bf(v0.x, v0.y); w.y = pk2bf(v0.z, v0.w);
    w.z = pk2bf(v1.x, v1.y); w.w = pk2bf(v1.z, v1.w);
    d4[i] = w;
  }
}

__global__ void k_scatter(const int* __restrict__ eidx,
                          int* __restrict__ sorted_slots, int* __restrict__ counts) {
  int slot = blockIdx.x * blockDim.x + threadIdx.x;
  if (slot >= NSLOT) return;
  int e = eidx[slot];
  int j = atomicAdd(counts + e, 1);
  if (j < CAP) sorted_slots[e * CAP + j] = slot;
}

// Staging: 4x global_load_lds_dwordx4 per thread per K-step.
// Source address carries the XOR swizzle (chunk kq^sw), LDS dest is linear ->
// the LDS image is byte-identical to the previous verified write-side swizzle.
#define STAGE1(bb, ko)                                              \
  ldst16(&smA[bb][(wave * 16) * BK], pA0 + (ko));                   \
  ldst16(&smA[bb][(64 + wave * 16) * BK], pA1 + (ko));              \
  ldst16(&smB[bb][(wave * 16) * BK], pB0 + (ko));                   \
  ldst16(&smB[bb][(64 + wave * 16) * BK], pB1 + (ko));

// GEMM1: h_act[row, i] = swiglu( t[tok] . Wg[e, 2i / 2i+1, :] + bias )
// y < CVT_Y blocks convert Wd fp32->bf16 (overlaps GEMM compute).
__global__ __launch_bounds__(NTH) void k_gemm1(
    const unsigned short* __restrict__ t_bf, const unsigned short* __restrict__ Wg_bf,
    const float* __restrict__ bg, const int* __restrict__ sorted_slots,
    const int* __restrict__ counts, unsigned short* __restrict__ h_act,
    const float* __restrict__ Wd, unsigned short* __restrict__ Wd_bf) {
  if (blockIdx.y < CVT_Y) {
    // Wd conversion: 512 blocks, 256 MB read + 128 MB write, hides under GEMM1
    int i = (blockIdx.y * gridDim.x + blockIdx.x) * NTH + threadIdx.x;
    const int stride = CVT_Y * (C1 / TN) * NTH;   // 131072
    const float4* s4 = (const float4*)Wd;
    uint4* d4 = (uint4*)Wd_bf;
    for (; i < N8_WD; i += stride) {
      float4 v0 = s4[2 * i], v1 = s4[2 * i + 1];
      uint4 w;
      w.x = pk2bf(v0.x, v0.y); w.y = pk2bf(v0.z, v0.w);
      w.z = pk2bf(v1.x, v1.y); w.w = pk2bf(v1.z, v1.w);
      d4[i] = w;
    }
    return;
  }
  const int yb = blockIdx.y - CVT_Y;
  const int e = yb >> 2;
  const int m0 = (yb & 3) * TM;
  int cnt = counts[e]; cnt = cnt > CAP ? CAP : cnt;
  if (m0 >= cnt) return;
  const int mr = min(cnt - m0, TM);
  const int c0 = blockIdx.x * TN;
  const int base = e * CAP + m0;

  __shared__ unsigned short smA[2][TM * BK];  // 2 x 8 KB
  __shared__ unsigned short smB[2][TN * BK];  // 2 x 8 KB

  const int tid = threadIdx.x;
  const int kq = tid & 3;                  // 16B chunk within BK row
  const int r0 = tid >> 2;                 // 0..63
  const int r1 = r0 + 64;
  const int sw = (r0 >> 1) & 3;            // swizzle key (same for r0 and r1)
  const int q8 = (kq ^ sw) * 8;            // pre-swizzled global chunk offset (elems)

  const int wave = tid >> 6;
  const int lane = tid & 63;
  const int wm = wave & 1, wn = wave >> 1;
  const int l15 = lane & 15;
  const int kc = lane >> 4;
  const int kcs = (kc ^ ((l15 >> 1) & 3)) * 8;   // swizzled read offset (elems)

  const int tok0 = sorted_slots[base + r0] >> 2;
  const int tok1 = sorted_slots[base + r1] >> 2;
  const unsigned short* pA0 = t_bf + (size_t)tok0 * H_DIM + q8;
  const unsigned short* pA1 = t_bf + (size_t)tok1 * H_DIM + q8;
  const unsigned short* pB0 = Wg_bf + ((size_t)e * C1 + (size_t)(c0 + r0)) * H_DIM + q8;
  const unsigned short* pB1 = Wg_bf + ((size_t)e * C1 + (size_t)(c0 + r1)) * H_DIM + q8;

  floatx4 acc[4][4];
#pragma unroll
  for (int i = 0; i < 4; ++i)
#pragma unroll
    for (int j = 0; j < 4; ++j) acc[i][j] = (floatx4){0.f, 0.f, 0.f, 0.f};

  STAGE1(0, 0);
  const int nk = H_DIM / BK;
#pragma unroll 2
  for (int kk = 0; kk < nk; ++kk) {
    __syncthreads();   // drains vmcnt of prior STAGE + own lgkmcnt before reuse
    const int buf = kk & 1;
    if (kk + 1 < nk) {
      const int ko = (kk + 1) * BK;
      if (buf == 0) { STAGE1(1, ko); } else { STAGE1(0, ko); }
    }
    short8 af[4], bfr[4];
#pragma unroll
    for (int i = 0; i < 4; ++i)
      af[i] = *(const short8*)&smA[buf][(wm * 64 + i * 16 + l15) * BK + kcs];
#pragma unroll
    for (int j = 0; j < 4; ++j)
      bfr[j] = *(const short8*)&smB[buf][(wn * 64 + j * 16 + l15) * BK + kcs];
#pragma unroll
    for (int i = 0; i < 4; ++i)
#pragma unroll
      for (int j = 0; j < 4; ++j)
        acc[i][j] = __builtin_amdgcn_mfma_f32_16x16x32_bf16(af[i], bfr[j], acc[i][j], 0, 0, 0);
  }

  // Epilogue: bias, pair (even c = glu, odd c = lin) via shfl, swiglu, store bf16.
  const int rq = (lane >> 4) * 4;
#pragma unroll
  for (int j = 0; j < 4; ++j) {
    const int c = c0 + wn * 64 + j * 16 + l15;   // c parity == lane parity
    const float bias = bg[e * C1 + c];
    const int ic = c >> 1;
#pragma unroll
    for (int i = 0; i < 4; ++i) {
      const int rbase = wm * 64 + i * 16 + rq;
#pragma unroll
      for (int r = 0; r < 4; ++r) {
        float v = acc[i][j][r] + bias;
        float o = __shfl_xor(v, 1);
        if ((lane & 1) == 0) {
          float xg = fminf(v, 7.0f);
          float xl = fminf(fmaxf(o, -7.0f), 7.0f);
          float res = (xg / (1.0f + __expf(-1.702f * xg))) * (xl + 1.0f);
          const int rl = rbase + r;
          if (rl < mr) h_act[(size_t)(base + rl) * I_DIM + ic] = f2bf(res);
        }
      }
    }
  }
}

// GEMM2: out[slot, c] = h_act[row,:] . Wd[e, c, :] + bias
__global__ __launch_bounds__(NTH) void k_gemm2(
    const unsigned short* __restrict__ h_act, const unsigned short* __restrict__ Wd_bf,
    const float* __restrict__ bd, const int* __restrict__ sorted_slots,
    const int* __restrict__ counts, float* __restrict__ out) {
  const int e = blockIdx.y >> 2;
  const int m0 = (blockIdx.y & 3) * TM;
  int cnt = counts[e]; cnt = cnt > CAP ? CAP : cnt;
  if (m0 >= cnt) return;
  const int mr = min(cnt - m0, TM);
  const int c0 = blockIdx.x * TN;
  const int base = e * CAP + m0;

  __shared__ unsigned short smA[2][TM * BK];
  __shared__ unsigned short smB[2][TN * BK];

  const int tid = threadIdx.x;
  const int kq = tid & 3;
  const int r0 = tid >> 2;
  const int r1 = r0 + 64;
  const int sw = (r0 >> 1) & 3;
  const int q8 = (kq ^ sw) * 8;

  const int wave = tid >> 6;
  const int lane = tid & 63;
  const int wm = wave & 1, wn = wave >> 1;
  const int l15 = lane & 15;
  const int kc = lane >> 4;
  const int kcs = (kc ^ ((l15 >> 1) & 3)) * 8;

  const unsigned short* pA0 = h_act + (size_t)(base + r0) * I_DIM + q8;
  const unsigned short* pA1 = h_act + (size_t)(base + r1) * I_DIM + q8;
  const unsigned short* pB0 = Wd_bf + ((size_t)e * H_DIM + (size_t)(c0 + r0)) * I_DIM + q8;
  const unsigned short* pB1 = Wd_bf + ((size_t)e * H_DIM + (size_t)(c0 + r1)) * I_DIM + q8;

  floatx4 acc[4][4];
#pragma unroll
  for (int i = 0; i < 4; ++i)
#pragma unroll
    for (int j = 0; j < 4; ++j) acc[i][j] = (floatx4){0.f, 0.f, 0.f, 0.f};

  STAGE1(0, 0);
  const int nk = I_DIM / BK;
#pragma unroll 2
  for (int kk = 0; kk < nk; ++kk) {
    __syncthreads();
    const int buf = kk & 1;
    if (kk + 1 < nk) {
      const int ko = (kk + 1) * BK;
      if (buf == 0) { STAGE1(1, ko); } else { STAGE1(0, ko); }
    }
    short8 af[4], bfr[4];
#pragma unroll
    for (int i = 0; i < 4; ++i)
      af[i] = *(const short8*)&smA[buf][(wm * 64 + i * 16 + l15) * BK + kcs];
#pragma unroll
    for (int j = 0; j < 4; ++j)
      bfr[j] = *(const short8*)&smB[buf][(wn * 64 + j * 16 + l15) * BK + kcs];
#pragma unroll
    for (int i = 0; i < 4; ++i)
#pragma unroll
      for (int j = 0; j < 4; ++j)
        acc[i][j] = __builtin_amdgcn_mfma_f32_16x16x32_bf16(af[i], bfr[j], acc[i][j], 0, 0, 0);
  }

  const int rq = (lane >> 4) * 4;
#pragma unroll
  for (int j = 0; j < 4; ++j) {
    const int c = c0 + wn * 64 + j * 16 + l15;
    const float bias = bd[e * H_DIM + c];
#pragma unroll
    for (int i = 0; i < 4; ++i) {
      const int rbase = wm * 64 + i * 16 + rq;
#pragma unroll
      for (int r = 0; r < 4; ++r) {
        const int rl = rbase + r;
        if (rl < mr) {
          const int slot = sorted_slots[base + rl];
          out[(size_t)slot * H_DIM + c] = acc[i][j][r] + bias;
        }
      }
    }
  }
}

extern "C" void kernel_launch(void* const* d_in, const int* in_sizes, int n_in,
                              void* d_out, int out_size, void* d_ws, size_t ws_size,
                              hipStream_t stream) {
  const float* t = (const float*)d_in[0];
  const int* eidx = (const int*)d_in[1];
  const float* Wg = (const float*)d_in[2];
  const float* bg = (const float*)d_in[3];
  const float* Wd = (const float*)d_in[4];
  const float* bd = (const float*)d_in[5];
  float* out = (float*)d_out;

  char* ws = (char*)d_ws;
  unsigned short* t_bf = (unsigned short*)ws;                                   //   0.. 4 MB
  unsigned short* h_act = (unsigned short*)(ws + (size_t)4 * 1024 * 1024);      //   4..36 MB
  int* sorted_slots = (int*)(ws + (size_t)36 * 1024 * 1024);                    //  36 MB + 32 KB
  int* counts = (int*)(ws + (size_t)36 * 1024 * 1024 + (size_t)SLOT_ROWS * 4);
  unsigned short* Wg_bf = (unsigned short*)(ws + (size_t)48 * 1024 * 1024);     //  48..304 MB
  unsigned short* Wd_bf = (unsigned short*)(ws + (size_t)304 * 1024 * 1024);    // 304..432 MB

  k_setup<<<dim3((B_TOK * H_DIM / 4) / 256), dim3(256), 0, stream>>>(t, t_bf, sorted_slots, counts, Wg, Wg_bf);
  k_scatter<<<dim3(NSLOT / 256), dim3(256), 0, stream>>>(eidx, sorted_slots, counts);
  k_gemm1<<<dim3(C1 / TN, CVT_Y + NEXP * (CAP / TM)), dim3(NTH), 0, stream>>>(t_bf, Wg_bf, bg, sorted_slots, counts, h_act, Wd, Wd_bf);
  k_gemm2<<<dim3(H_DIM / TN, NEXP * (CAP / TM)), dim3(NTH), 0, stream>>>(h_act, Wd_bf, bd, sorted_slots, counts, out);
}